// Round 2
// baseline (87.381 us; speedup 1.0000x reference)
//
#include <hip/hip_runtime.h>

#define WW 512
#define HH 512
#define CC 64
#define HW (HH*WW)

__device__ __forceinline__ void invert3(const float* __restrict__ m, float* o) {
    float a = m[0], b = m[1], c = m[2];
    float d = m[3], e = m[4], f = m[5];
    float g = m[6], h = m[7], i = m[8];
    float C11 =  (e*i - f*h);
    float C12 = -(d*i - f*g);
    float C13 =  (d*h - e*g);
    float C21 = -(b*i - c*h);
    float C22 =  (a*i - c*g);
    float C23 = -(a*h - b*g);
    float C31 =  (b*f - c*e);
    float C32 = -(a*f - c*d);
    float C33 =  (a*e - b*d);
    float det = a*C11 + b*C12 + c*C13;
    float id = 1.0f / det;
    o[0] = C11*id; o[1] = C21*id; o[2] = C31*id;
    o[3] = C12*id; o[4] = C22*id; o[5] = C32*id;
    o[6] = C13*id; o[7] = C23*id; o[8] = C33*id;
}

__device__ __forceinline__ void reproj_pt(
    float px, float py, float d,
    const float Kinv[9],
    const float* __restrict__ cf, const float* __restrict__ ct,
    const float* __restrict__ Kt,
    float& ox, float& oy)
{
    float cx = Kinv[0]*px + Kinv[1]*py + Kinv[2];
    float cy = Kinv[3]*px + Kinv[4]*py + Kinv[5];
    float cz = Kinv[6]*px + Kinv[7]*py + Kinv[8];
    cx *= d; cy *= d; cz *= d;
    float wx = cf[0]*cx + cf[1]*cy + cf[2]*cz + cf[3];
    float wy = cf[4]*cx + cf[5]*cy + cf[6]*cz + cf[7];
    float wz = cf[8]*cx + cf[9]*cy + cf[10]*cz + cf[11];
    float qx = wx - ct[3], qy = wy - ct[7], qz = wz - ct[11];
    float ax = ct[0]*qx + ct[4]*qy + ct[8]*qz;
    float ay = ct[1]*qx + ct[5]*qy + ct[9]*qz;
    float az = ct[2]*qx + ct[6]*qy + ct[10]*qz;
    float p0 = Kt[0]*ax + Kt[1]*ay + Kt[2]*az;
    float p1 = Kt[3]*ax + Kt[4]*ay + Kt[5]*az;
    float p2 = Kt[6]*ax + Kt[7]*ay + Kt[8]*az;
    float zs = (fabsf(p2) > 1e-6f) ? p2 : 1e-6f;
    float u = p0 / zs;
    float v = p1 / zs;
    ox = u / 512.0f * 2.0f - 1.0f;
    oy = v / 512.0f * 2.0f - 1.0f;
}

// Block = 256 threads = 4 waves. Each block owns 64 pixels (one per lane);
// wave w computes channels [16w, 16w+16). Per-pixel setup is recomputed by
// all 4 waves (VALU is idle; this avoids an LDS handoff + barrier).
__global__ __launch_bounds__(256) void reproj_loss_kernel(
    const float* __restrict__ f1, const float* __restrict__ f2,
    const float* __restrict__ d1p, const float* __restrict__ d2p,
    const float* __restrict__ m1p,
    const float* __restrict__ K1, const float* __restrict__ K2,
    const float* __restrict__ cw1, const float* __restrict__ cw2,
    float* __restrict__ out)
{
    int wave = threadIdx.x >> 6;
    int lane = threadIdx.x & 63;
    int pix  = blockIdx.x * 64 + lane;
    int j = pix & (WW - 1);
    int i = pix >> 9;

    float Ki1[9], Ki2[9];
    invert3(K1, Ki1);
    invert3(K2, Ki2);

    float px = j + 0.5f, py = i + 0.5f;

    float l12x, l12y;
    reproj_pt(px, py, d1p[pix], Ki1, cw1, cw2, K2, l12x, l12y);
    float l21x, l21y;
    reproj_pt(px, py, d2p[pix], Ki2, cw2, cw1, K1, l21x, l21y);

    // bilinear setup at l1_2 (for l2_1-field sample and f1_2)
    float axf = (l12x + 1.0f) * 256.0f - 0.5f;
    float ayf = (l12y + 1.0f) * 256.0f - 0.5f;
    float ax0 = floorf(axf), ay0 = floorf(ayf);
    float awx = axf - ax0, awy = ayf - ay0;
    ax0 = fminf(fmaxf(ax0, -1e8f), 1e8f);
    ay0 = fminf(fmaxf(ay0, -1e8f), 1e8f);
    int ax0i = (int)ax0, ay0i = (int)ay0;

    float wA[4];
    int   offA[4];
    float vx = 0.0f, vy = 0.0f;
    #pragma unroll
    for (int k = 0; k < 4; ++k) {
        int dx = k & 1, dy = k >> 1;
        int ix = ax0i + dx, iy = ay0i + dy;
        float w = (dx ? awx : 1.0f - awx) * (dy ? awy : 1.0f - awy);
        bool valid = (ix >= 0) && (ix < WW) && (iy >= 0) && (iy < HH);
        if (valid) {
            int off = iy * WW + ix;
            wA[k] = w; offA[k] = off;
            float cxv, cyv;
            reproj_pt(ix + 0.5f, iy + 0.5f, d2p[off], Ki2, cw2, cw1, K1, cxv, cyv);
            vx += w * cxv;
            vy += w * cyv;
        } else {
            wA[k] = 0.0f; offA[k] = 0;
        }
    }

    float gx = (j + 0.5f) / 512.0f * 2.0f - 1.0f;
    float gy = (i + 0.5f) / 512.0f * 2.0f - 1.0f;
    float ddx = gx - vx, ddy = gy - vy;
    float dist = sqrtf(ddx * ddx + ddy * ddy);
    float wgt = (dist < 0.0025f) ? m1p[pix] : 0.0f;

    float lsum = 0.0f;
    if (__any(wgt != 0.0f)) {
        // bilinear setup at l2_1 (for f2_1)
        float bxf = (l21x + 1.0f) * 256.0f - 0.5f;
        float byf = (l21y + 1.0f) * 256.0f - 0.5f;
        float bx0 = floorf(bxf), by0 = floorf(byf);
        float bwx = bxf - bx0, bwy = byf - by0;
        bx0 = fminf(fmaxf(bx0, -1e8f), 1e8f);
        by0 = fminf(fmaxf(by0, -1e8f), 1e8f);
        int bx0i = (int)bx0, by0i = (int)by0;

        float wB[4];
        int   offB[4];
        #pragma unroll
        for (int k = 0; k < 4; ++k) {
            int dx = k & 1, dy = k >> 1;
            int ix = bx0i + dx, iy = by0i + dy;
            float w = (dx ? bwx : 1.0f - bwx) * (dy ? bwy : 1.0f - bwy);
            bool valid = (ix >= 0) && (ix < WW) && (iy >= 0) && (iy < HH);
            wB[k]  = valid ? w : 0.0f;
            offB[k] = valid ? (iy * WW + ix) : 0;
        }

        float acc = 0.0f;
        const float* F1 = f1 + (size_t)(wave * 16) * HW;
        const float* F2 = f2 + (size_t)(wave * 16) * HW;
        #pragma unroll 4
        for (int c = 0; c < 16; ++c) {
            float s1 = F2[offA[0]]*wA[0] + F2[offA[1]]*wA[1]
                     + F2[offA[2]]*wA[2] + F2[offA[3]]*wA[3];
            float e1 = F1[pix] - s1;
            float s2 = F1[offB[0]]*wB[0] + F1[offB[1]]*wB[1]
                     + F1[offB[2]]*wB[2] + F1[offB[3]]*wB[3];
            float e2 = F2[pix] - s2;
            acc += e1 * e1 + e2 * e2;
            F1 += HW; F2 += HW;
        }
        lsum = wgt * acc;
    }

    // reduce: wave shuffle, then cross-wave via LDS
    #pragma unroll
    for (int off = 32; off > 0; off >>= 1)
        lsum += __shfl_down(lsum, off);
    __shared__ float sred[4];
    if (lane == 0) sred[wave] = lsum;
    __syncthreads();
    if (threadIdx.x == 0) {
        float t = (sred[0] + sred[1]) + (sred[2] + sred[3]);
        atomicAdd(out, t * (1.0f / 262144.0f));
    }
}

extern "C" void kernel_launch(void* const* d_in, const int* in_sizes, int n_in,
                              void* d_out, int out_size, void* d_ws, size_t ws_size,
                              hipStream_t stream) {
    const float* f1  = (const float*)d_in[0];
    const float* f2  = (const float*)d_in[1];
    const float* dp1 = (const float*)d_in[4];
    const float* dp2 = (const float*)d_in[5];
    const float* m1  = (const float*)d_in[6];
    const float* K1  = (const float*)d_in[8];
    const float* K2  = (const float*)d_in[9];
    const float* c1  = (const float*)d_in[10];
    const float* c2  = (const float*)d_in[11];

    float* out = (float*)d_out;
    hipMemsetAsync(out, 0, sizeof(float), stream);
    reproj_loss_kernel<<<HW / 64, 256, 0, stream>>>(
        f1, f2, dp1, dp2, m1, K1, K2, c1, c2, out);
}

// Round 3
// 86.762 us; speedup vs baseline: 1.0071x; 1.0071x over previous
//
#include <hip/hip_runtime.h>

#define WW 512
#define HH 512
#define CC 64
#define HW (HH*WW)

__device__ __forceinline__ void invert3(const float* __restrict__ m, float* o) {
    float a = m[0], b = m[1], c = m[2];
    float d = m[3], e = m[4], f = m[5];
    float g = m[6], h = m[7], i = m[8];
    float C11 =  (e*i - f*h);
    float C12 = -(d*i - f*g);
    float C13 =  (d*h - e*g);
    float C21 = -(b*i - c*h);
    float C22 =  (a*i - c*g);
    float C23 = -(a*h - b*g);
    float C31 =  (b*f - c*e);
    float C32 = -(a*f - c*d);
    float C33 =  (a*e - b*d);
    float det = a*C11 + b*C12 + c*C13;
    float id = 1.0f / det;
    o[0] = C11*id; o[1] = C21*id; o[2] = C31*id;
    o[3] = C12*id; o[4] = C22*id; o[5] = C32*id;
    o[6] = C13*id; o[7] = C23*id; o[8] = C33*id;
}

__device__ __forceinline__ void reproj_pt(
    float px, float py, float d,
    const float Kinv[9],
    const float* __restrict__ cf, const float* __restrict__ ct,
    const float* __restrict__ Kt,
    float& ox, float& oy)
{
    float cx = Kinv[0]*px + Kinv[1]*py + Kinv[2];
    float cy = Kinv[3]*px + Kinv[4]*py + Kinv[5];
    float cz = Kinv[6]*px + Kinv[7]*py + Kinv[8];
    cx *= d; cy *= d; cz *= d;
    float wx = cf[0]*cx + cf[1]*cy + cf[2]*cz + cf[3];
    float wy = cf[4]*cx + cf[5]*cy + cf[6]*cz + cf[7];
    float wz = cf[8]*cx + cf[9]*cy + cf[10]*cz + cf[11];
    float qx = wx - ct[3], qy = wy - ct[7], qz = wz - ct[11];
    float ax = ct[0]*qx + ct[4]*qy + ct[8]*qz;
    float ay = ct[1]*qx + ct[5]*qy + ct[9]*qz;
    float az = ct[2]*qx + ct[6]*qy + ct[10]*qz;
    float p0 = Kt[0]*ax + Kt[1]*ay + Kt[2]*az;
    float p1 = Kt[3]*ax + Kt[4]*ay + Kt[5]*az;
    float p2 = Kt[6]*ax + Kt[7]*ay + Kt[8]*az;
    float zs = (fabsf(p2) > 1e-6f) ? p2 : 1e-6f;
    float u = p0 / zs;
    float v = p1 / zs;
    ox = u / 512.0f * 2.0f - 1.0f;
    oy = v / 512.0f * 2.0f - 1.0f;
}

// Shared per-pixel setup logic (exact R1 arithmetic). Produces bilinear
// state for both sample points + the cycle-consistency weight.
__device__ __forceinline__ void pixel_setup(
    int pix,
    const float* __restrict__ d1p, const float* __restrict__ d2p,
    const float* __restrict__ m1p,
    const float* __restrict__ K1, const float* __restrict__ K2,
    const float* __restrict__ cw1, const float* __restrict__ cw2,
    float wA[4], int offA[4], float wB[4], int offB[4], float& wgt)
{
    int j = pix & (WW - 1);
    int i = pix >> 9;

    float Ki1[9], Ki2[9];
    invert3(K1, Ki1);
    invert3(K2, Ki2);

    float px = j + 0.5f, py = i + 0.5f;

    float l12x, l12y;
    reproj_pt(px, py, d1p[pix], Ki1, cw1, cw2, K2, l12x, l12y);
    float l21x, l21y;
    reproj_pt(px, py, d2p[pix], Ki2, cw2, cw1, K1, l21x, l21y);

    // bilinear setup at l1_2
    float axf = (l12x + 1.0f) * 256.0f - 0.5f;
    float ayf = (l12y + 1.0f) * 256.0f - 0.5f;
    float ax0 = floorf(axf), ay0 = floorf(ayf);
    float awx = axf - ax0, awy = ayf - ay0;
    ax0 = fminf(fmaxf(ax0, -1e8f), 1e8f);
    ay0 = fminf(fmaxf(ay0, -1e8f), 1e8f);
    int ax0i = (int)ax0, ay0i = (int)ay0;

    float vx = 0.0f, vy = 0.0f;
    #pragma unroll
    for (int k = 0; k < 4; ++k) {
        int dx = k & 1, dy = k >> 1;
        int ix = ax0i + dx, iy = ay0i + dy;
        float w = (dx ? awx : 1.0f - awx) * (dy ? awy : 1.0f - awy);
        bool valid = (ix >= 0) && (ix < WW) && (iy >= 0) && (iy < HH);
        if (valid) {
            int off = iy * WW + ix;
            wA[k] = w; offA[k] = off;
            float cxv, cyv;
            reproj_pt(ix + 0.5f, iy + 0.5f, d2p[off], Ki2, cw2, cw1, K1, cxv, cyv);
            vx += w * cxv;
            vy += w * cyv;
        } else {
            wA[k] = 0.0f; offA[k] = 0;
        }
    }

    float gx = (j + 0.5f) / 512.0f * 2.0f - 1.0f;
    float gy = (i + 0.5f) / 512.0f * 2.0f - 1.0f;
    float ddx = gx - vx, ddy = gy - vy;
    float dist = sqrtf(ddx * ddx + ddy * ddy);
    wgt = (dist < 0.0025f) ? m1p[pix] : 0.0f;

    // bilinear setup at l2_1
    float bxf = (l21x + 1.0f) * 256.0f - 0.5f;
    float byf = (l21y + 1.0f) * 256.0f - 0.5f;
    float bx0 = floorf(bxf), by0 = floorf(byf);
    float bwx = bxf - bx0, bwy = byf - by0;
    bx0 = fminf(fmaxf(bx0, -1e8f), 1e8f);
    by0 = fminf(fmaxf(by0, -1e8f), 1e8f);
    int bx0i = (int)bx0, by0i = (int)by0;
    #pragma unroll
    for (int k = 0; k < 4; ++k) {
        int dx = k & 1, dy = k >> 1;
        int ix = bx0i + dx, iy = by0i + dy;
        float w = (dx ? bwx : 1.0f - bwx) * (dy ? bwy : 1.0f - bwy);
        bool valid = (ix >= 0) && (ix < WW) && (iy >= 0) && (iy < HH);
        wB[k]  = valid ? w : 0.0f;
        offB[k] = valid ? (iy * WW + ix) : 0;
    }
}

// ---------- K1: per-pixel setup -> packed state in workspace ----------
__global__ __launch_bounds__(256) void setup_kernel(
    const float* __restrict__ d1p, const float* __restrict__ d2p,
    const float* __restrict__ m1p,
    const float* __restrict__ K1, const float* __restrict__ K2,
    const float* __restrict__ cw1, const float* __restrict__ cw2,
    float4* __restrict__ wA4, int4* __restrict__ offA4,
    float4* __restrict__ wB4, int4* __restrict__ offB4,
    float* __restrict__ wgtp)
{
    int pix = blockIdx.x * 256 + threadIdx.x;
    float wA[4], wB[4], wgt;
    int offA[4], offB[4];
    pixel_setup(pix, d1p, d2p, m1p, K1, K2, cw1, cw2, wA, offA, wB, offB, wgt);
    wA4[pix]  = make_float4(wA[0], wA[1], wA[2], wA[3]);
    offA4[pix] = make_int4(offA[0], offA[1], offA[2], offA[3]);
    wB4[pix]  = make_float4(wB[0], wB[1], wB[2], wB[3]);
    offB4[pix] = make_int4(offB[0], offB[1], offB[2], offB[3]);
    wgtp[pix] = wgt;
}

// ---------- K2: pure gather loop, channel-split by blockIdx.y ----------
__global__ __launch_bounds__(256) void gather_kernel(
    const float* __restrict__ f1, const float* __restrict__ f2,
    const float4* __restrict__ wA4, const int4* __restrict__ offA4,
    const float4* __restrict__ wB4, const int4* __restrict__ offB4,
    const float* __restrict__ wgtp, float* __restrict__ out)
{
    int pix = blockIdx.x * 256 + threadIdx.x;
    float wgt = wgtp[pix];
    float lsum = 0.0f;

    if (wgt != 0.0f) {
        float4 wA = wA4[pix];  int4 oA = offA4[pix];
        float4 wB = wB4[pix];  int4 oB = offB4[pix];
        const float* F1 = f1 + (size_t)blockIdx.y * 16 * HW;
        const float* F2 = f2 + (size_t)blockIdx.y * 16 * HW;
        float acc = 0.0f;
        #pragma unroll
        for (int c = 0; c < 16; c += 2) {
            const float* G1 = F1 + HW;
            const float* G2 = F2 + HW;
            // batch all loads of two channel planes before consuming
            float a0 = F2[oA.x], a1 = F2[oA.y], a2 = F2[oA.z], a3 = F2[oA.w];
            float b0 = F1[oB.x], b1 = F1[oB.y], b2 = F1[oB.z], b3 = F1[oB.w];
            float p1 = F1[pix],  p2 = F2[pix];
            float c0 = G2[oA.x], c1 = G2[oA.y], c2 = G2[oA.z], c3 = G2[oA.w];
            float d0 = G1[oB.x], d1 = G1[oB.y], d2 = G1[oB.z], d3 = G1[oB.w];
            float q1 = G1[pix],  q2 = G2[pix];

            float s1a = a0*wA.x + a1*wA.y + a2*wA.z + a3*wA.w;
            float s2a = b0*wB.x + b1*wB.y + b2*wB.z + b3*wB.w;
            float e1a = p1 - s1a;
            float e2a = p2 - s2a;
            float s1b = c0*wA.x + c1*wA.y + c2*wA.z + c3*wA.w;
            float s2b = d0*wB.x + d1*wB.y + d2*wB.z + d3*wB.w;
            float e1b = q1 - s1b;
            float e2b = q2 - s2b;
            acc += e1a*e1a + e2a*e2a + e1b*e1b + e2b*e2b;
            F1 += 2 * HW;
            F2 += 2 * HW;
        }
        lsum = wgt * acc;
    }

    #pragma unroll
    for (int off = 32; off > 0; off >>= 1)
        lsum += __shfl_down(lsum, off);
    __shared__ float sred[4];
    int wave = threadIdx.x >> 6;
    if ((threadIdx.x & 63) == 0) sred[wave] = lsum;
    __syncthreads();
    if (threadIdx.x == 0) {
        float t = (sred[0] + sred[1]) + (sred[2] + sred[3]);
        atomicAdd(out, t * (1.0f / 262144.0f));
    }
}

// ---------- fallback: R1 monolithic kernel (used if ws too small) ----------
__global__ __launch_bounds__(256) void mono_kernel(
    const float* __restrict__ f1, const float* __restrict__ f2,
    const float* __restrict__ d1p, const float* __restrict__ d2p,
    const float* __restrict__ m1p,
    const float* __restrict__ K1, const float* __restrict__ K2,
    const float* __restrict__ cw1, const float* __restrict__ cw2,
    float* __restrict__ out)
{
    int pix = blockIdx.x * 256 + threadIdx.x;
    float wA[4], wB[4], wgt;
    int offA[4], offB[4];
    pixel_setup(pix, d1p, d2p, m1p, K1, K2, cw1, cw2, wA, offA, wB, offB, wgt);

    float lsum = 0.0f;
    if (wgt != 0.0f) {
        float acc = 0.0f;
        const float* F1 = f1;
        const float* F2 = f2;
        for (int c = 0; c < CC; ++c) {
            float s1 = F2[offA[0]]*wA[0] + F2[offA[1]]*wA[1]
                     + F2[offA[2]]*wA[2] + F2[offA[3]]*wA[3];
            float e1 = F1[pix] - s1;
            float s2 = F1[offB[0]]*wB[0] + F1[offB[1]]*wB[1]
                     + F1[offB[2]]*wB[2] + F1[offB[3]]*wB[3];
            float e2 = F2[pix] - s2;
            acc += e1 * e1 + e2 * e2;
            F1 += HW; F2 += HW;
        }
        lsum = wgt * acc;
    }

    #pragma unroll
    for (int off = 32; off > 0; off >>= 1)
        lsum += __shfl_down(lsum, off);
    __shared__ float sred[4];
    if ((threadIdx.x & 63) == 0) sred[threadIdx.x >> 6] = lsum;
    __syncthreads();
    if (threadIdx.x == 0) {
        float t = (sred[0] + sred[1]) + (sred[2] + sred[3]);
        atomicAdd(out, t * (1.0f / 262144.0f));
    }
}

extern "C" void kernel_launch(void* const* d_in, const int* in_sizes, int n_in,
                              void* d_out, int out_size, void* d_ws, size_t ws_size,
                              hipStream_t stream) {
    const float* f1  = (const float*)d_in[0];
    const float* f2  = (const float*)d_in[1];
    const float* dp1 = (const float*)d_in[4];
    const float* dp2 = (const float*)d_in[5];
    const float* m1  = (const float*)d_in[6];
    const float* K1  = (const float*)d_in[8];
    const float* K2  = (const float*)d_in[9];
    const float* c1  = (const float*)d_in[10];
    const float* c2  = (const float*)d_in[11];

    float* out = (float*)d_out;
    hipMemsetAsync(out, 0, sizeof(float), stream);

    const size_t need = (size_t)HW * (16 + 16 + 16 + 16 + 4); // 17.8 MB
    if (ws_size >= need) {
        char* ws = (char*)d_ws;
        float4* wA4  = (float4*)(ws);
        int4*  offA4 = (int4*)(ws + (size_t)HW * 16);
        float4* wB4  = (float4*)(ws + (size_t)HW * 32);
        int4*  offB4 = (int4*)(ws + (size_t)HW * 48);
        float* wgtp  = (float*)(ws + (size_t)HW * 64);

        setup_kernel<<<HW / 256, 256, 0, stream>>>(
            dp1, dp2, m1, K1, K2, c1, c2, wA4, offA4, wB4, offB4, wgtp);
        gather_kernel<<<dim3(HW / 256, 4), 256, 0, stream>>>(
            f1, f2, wA4, offA4, wB4, offB4, wgtp, out);
    } else {
        mono_kernel<<<HW / 256, 256, 0, stream>>>(
            f1, f2, dp1, dp2, m1, K1, K2, c1, c2, out);
    }
}